// Round 1
// baseline (1172.066 us; speedup 1.0000x reference)
//
#include <hip/hip_runtime.h>
#include <cstdint>

#define TOK   8192
#define DIM   1024
#define NE    8
#define HID   4096
#define CAP   8320
#define HROWS 17408

typedef __attribute__((ext_vector_type(4))) float f32x4;
typedef __attribute__((ext_vector_type(8))) short s16x8;

__device__ inline unsigned short f2bf(float f) {
  union { float f; unsigned u; } v; v.f = f;
  unsigned r = v.u + 0x7FFFu + ((v.u >> 16) & 1u);
  return (unsigned short)(r >> 16);
}

// ---------------- cast x (fp32 -> bf16) ----------------
__global__ __launch_bounds__(256) void cast_x_kernel(const float* __restrict__ x,
                                                     unsigned short* __restrict__ xb) {
  size_t i = ((size_t)blockIdx.x * 256 + threadIdx.x) * 4;
  f32x4 v = *(const f32x4*)(x + i);
  ushort4 o;
  o.x = f2bf(v[0]); o.y = f2bf(v[1]); o.z = f2bf(v[2]); o.w = f2bf(v[3]);
  *(ushort4*)(xb + i) = o;
}

// ---------------- transpose+cast W [E][K][N] fp32 -> Wt [E][N][K] bf16 ----------------
__global__ __launch_bounds__(256) void transpose_cast_kernel(const float* __restrict__ W,
                                                             unsigned short* __restrict__ Wt,
                                                             int K, int N) {
  int e = blockIdx.z;
  int n0 = blockIdx.x * 64;
  int k0 = blockIdx.y * 64;
  const float* We = W + (size_t)e * K * N;
  unsigned short* Wte = Wt + (size_t)e * K * N;
  __shared__ float tile[64][65];
  int tid = threadIdx.x;
  int c4 = (tid & 15) * 4;  // 0..60
  int r  = tid >> 4;        // 0..15
#pragma unroll
  for (int rr = 0; rr < 64; rr += 16) {
    f32x4 v = *(const f32x4*)(We + (size_t)(k0 + r + rr) * N + n0 + c4);
    tile[r + rr][c4 + 0] = v[0];
    tile[r + rr][c4 + 1] = v[1];
    tile[r + rr][c4 + 2] = v[2];
    tile[r + rr][c4 + 3] = v[3];
  }
  __syncthreads();
#pragma unroll
  for (int rr = 0; rr < 64; rr += 16) {
    int n = r + rr;
    ushort4 o;
    o.x = f2bf(tile[c4 + 0][n]);
    o.y = f2bf(tile[c4 + 1][n]);
    o.z = f2bf(tile[c4 + 2][n]);
    o.w = f2bf(tile[c4 + 3][n]);
    *(ushort4*)(Wte + (size_t)(n0 + n) * K + k0 + c4) = o;
  }
}

// ---------------- router: one wave per token, fp32 exact ----------------
__global__ __launch_bounds__(256) void router_kernel(const float* __restrict__ x,
                                                     const float* __restrict__ noise,
                                                     const float* __restrict__ Wg,
                                                     const float* __restrict__ bg,
                                                     const float* __restrict__ Wn,
                                                     const float* __restrict__ bn,
                                                     int* __restrict__ cnt,
                                                     int* __restrict__ tokL,
                                                     float* __restrict__ gateL) {
  int t = blockIdx.x * 4 + (threadIdx.x >> 6);
  int lane = threadIdx.x & 63;
  float ag[8] = {0, 0, 0, 0, 0, 0, 0, 0};
  float an[8] = {0, 0, 0, 0, 0, 0, 0, 0};
  const float* xr = x + (size_t)t * DIM;
  for (int d = lane; d < DIM; d += 64) {
    float xv = xr[d];
    f32x4 g0 = *(const f32x4*)(Wg + d * 8);
    f32x4 g1 = *(const f32x4*)(Wg + d * 8 + 4);
    f32x4 n0 = *(const f32x4*)(Wn + d * 8);
    f32x4 n1 = *(const f32x4*)(Wn + d * 8 + 4);
    ag[0] += xv * g0[0]; ag[1] += xv * g0[1]; ag[2] += xv * g0[2]; ag[3] += xv * g0[3];
    ag[4] += xv * g1[0]; ag[5] += xv * g1[1]; ag[6] += xv * g1[2]; ag[7] += xv * g1[3];
    an[0] += xv * n0[0]; an[1] += xv * n0[1]; an[2] += xv * n0[2]; an[3] += xv * n0[3];
    an[4] += xv * n1[0]; an[5] += xv * n1[1]; an[6] += xv * n1[2]; an[7] += xv * n1[3];
  }
#pragma unroll
  for (int off = 32; off >= 1; off >>= 1) {
#pragma unroll
    for (int e = 0; e < 8; e++) {
      ag[e] += __shfl_xor(ag[e], off);
      an[e] += __shfl_xor(an[e], off);
    }
  }
  if (lane == 0) {
    float v[8];
#pragma unroll
    for (int e = 0; e < 8; e++) {
      float lg = ag[e] + bg[e];
      float ln = an[e] + bn[e];
      float sp = (ln > 20.f) ? ln : log1pf(expf(ln));  // stable softplus
      v[e] = lg + noise[(size_t)t * 8 + e] * sp;
    }
    int i1 = 0; float m1 = v[0];
#pragma unroll
    for (int e = 1; e < 8; e++) { if (v[e] > m1) { m1 = v[e]; i1 = e; } }
    int i2 = -1; float m2 = -1e30f;
#pragma unroll
    for (int e = 0; e < 8; e++) { if (e != i1 && v[e] > m2) { m2 = v[e]; i2 = e; } }
    float e2 = expf(m2 - m1);
    float denom = 1.f + e2;
    float g1 = 1.f / denom;
    float g2 = e2 / denom;
    int p1 = atomicAdd(&cnt[i1], 1);
    tokL[i1 * CAP + p1] = t; gateL[i1 * CAP + p1] = g1;
    int p2 = atomicAdd(&cnt[i2], 1);
    tokL[i2 * CAP + p2] = t; gateL[i2 * CAP + p2] = g2;
  }
}

// ---------------- pad lists to 128-multiples; prefix-sum h offsets ----------------
__global__ __launch_bounds__(256) void pad_kernel(const int* __restrict__ cnt,
                                                  int* __restrict__ hoff,
                                                  int* __restrict__ tokL,
                                                  float* __restrict__ gateL) {
  __shared__ int cp_s[8];
  if (threadIdx.x == 0) {
    int off = 0;
    for (int e = 0; e < 8; e++) {
      int c = cnt[e];
      int cp = (c + 127) & ~127;
      cp_s[e] = cp;
      hoff[e] = off;
      off += cp;
    }
  }
  __syncthreads();
  for (int e = 0; e < 8; e++) {
    int c = cnt[e], cp = cp_s[e];
    for (int i = c + threadIdx.x; i < cp; i += 256) {
      tokL[e * CAP + i] = 0;
      gateL[e * CAP + i] = 0.f;
    }
  }
}

// ---------------- GEMM1: h = relu(gather(x) @ W1[e] + b1[e]) ----------------
// A: xb gathered rows [cp_e][1024] bf16; B: w1t[e] = [4096][1024] bf16 (N-major)
__global__ __launch_bounds__(256) void gemm1_kernel(const unsigned short* __restrict__ xb,
                                                    const unsigned short* __restrict__ w1t,
                                                    const float* __restrict__ b1,
                                                    const int* __restrict__ tokL,
                                                    const int* __restrict__ cnt,
                                                    const int* __restrict__ hoff,
                                                    unsigned short* __restrict__ h) {
  const int e = blockIdx.z;
  const int c = cnt[e];
  const int cp = (c + 127) & ~127;
  const int rb = blockIdx.y;
  if (rb * 128 >= cp) return;
  const int nb = blockIdx.x;
  const int row0 = hoff[e] + rb * 128;

  __shared__ unsigned short As[128 * 40];
  __shared__ unsigned short Bs[128 * 40];
  __shared__ int toks[128];

  const int tid = threadIdx.x;
  if (tid < 128) toks[tid] = tokL[e * CAP + rb * 128 + tid];
  __syncthreads();

  const int ar = tid >> 2;         // 0..63 staging row
  const int ac = (tid & 3) << 3;   // 0,8,16,24 bf16 col
  const unsigned short* xr0 = xb + (size_t)toks[ar] * DIM + ac;
  const unsigned short* xr1 = xb + (size_t)toks[64 + ar] * DIM + ac;
  const unsigned short* bp = w1t + (size_t)e * HID * DIM + (size_t)(nb * 128) * DIM + ac;
  const unsigned short* br0 = bp + (size_t)ar * DIM;
  const unsigned short* br1 = bp + (size_t)(64 + ar) * DIM;

  const int lane = tid & 63;
  const int w = tid >> 6;
  const int wm = (w >> 1) * 64;
  const int wn = (w & 1) * 64;
  const int fr = lane & 15;
  const int fq = lane >> 4;

  f32x4 acc[4][4];
#pragma unroll
  for (int i = 0; i < 4; i++)
#pragma unroll
    for (int j = 0; j < 4; j++) acc[i][j] = (f32x4){0.f, 0.f, 0.f, 0.f};

  for (int k0 = 0; k0 < DIM; k0 += 32) {
    f32x4 a0 = *(const f32x4*)(xr0 + k0);
    f32x4 a1 = *(const f32x4*)(xr1 + k0);
    f32x4 b0 = *(const f32x4*)(br0 + k0);
    f32x4 b1v = *(const f32x4*)(br1 + k0);
    __syncthreads();
    *(f32x4*)(As + ar * 40 + ac) = a0;
    *(f32x4*)(As + (64 + ar) * 40 + ac) = a1;
    *(f32x4*)(Bs + ar * 40 + ac) = b0;
    *(f32x4*)(Bs + (64 + ar) * 40 + ac) = b1v;
    __syncthreads();
    s16x8 af[4], bf[4];
#pragma unroll
    for (int i = 0; i < 4; i++) af[i] = *(const s16x8*)(As + (wm + i * 16 + fr) * 40 + fq * 8);
#pragma unroll
    for (int j = 0; j < 4; j++) bf[j] = *(const s16x8*)(Bs + (wn + j * 16 + fr) * 40 + fq * 8);
#pragma unroll
    for (int i = 0; i < 4; i++)
#pragma unroll
      for (int j = 0; j < 4; j++)
        acc[i][j] = __builtin_amdgcn_mfma_f32_16x16x32_bf16(af[i], bf[j], acc[i][j], 0, 0, 0);
  }

  const float* b1p = b1 + (size_t)e * HID + nb * 128 + wn;
#pragma unroll
  for (int j = 0; j < 4; j++) {
    float bias = b1p[j * 16 + fr];
#pragma unroll
    for (int i = 0; i < 4; i++)
#pragma unroll
      for (int v = 0; v < 4; v++) {
        float val = acc[i][j][v] + bias;
        val = fmaxf(val, 0.f);
        int m = wm + i * 16 + fq * 4 + v;
        h[(size_t)(row0 + m) * HID + nb * 128 + wn + j * 16 + fr] = f2bf(val);
      }
  }
}

// ---------------- GEMM2: out[tok] += gate * (h @ W2[e] + b2[e]) ----------------
// A: h rows [cp_e][4096] bf16; B: w2t[e] = [1024][4096] bf16 (N-major)
__global__ __launch_bounds__(256) void gemm2_kernel(const unsigned short* __restrict__ h,
                                                    const unsigned short* __restrict__ w2t,
                                                    const float* __restrict__ b2,
                                                    const int* __restrict__ tokL,
                                                    const float* __restrict__ gateL,
                                                    const int* __restrict__ cnt,
                                                    const int* __restrict__ hoff,
                                                    float* __restrict__ out) {
  const int e = blockIdx.z;
  const int c = cnt[e];
  const int cp = (c + 127) & ~127;
  const int rb = blockIdx.y;
  if (rb * 128 >= cp) return;
  const int nb = blockIdx.x;
  const int row0 = hoff[e] + rb * 128;

  __shared__ unsigned short As[128 * 40];
  __shared__ unsigned short Bs[128 * 40];
  __shared__ int toks[128];
  __shared__ float gts[128];

  const int tid = threadIdx.x;
  if (tid < 128) {
    toks[tid] = tokL[e * CAP + rb * 128 + tid];
    gts[tid] = gateL[e * CAP + rb * 128 + tid];
  }
  __syncthreads();

  const int ar = tid >> 2;
  const int ac = (tid & 3) << 3;
  const unsigned short* ha0 = h + (size_t)(row0 + ar) * HID + ac;
  const unsigned short* ha1 = h + (size_t)(row0 + 64 + ar) * HID + ac;
  const unsigned short* bp = w2t + (size_t)e * DIM * HID + (size_t)(nb * 128) * HID + ac;
  const unsigned short* br0 = bp + (size_t)ar * HID;
  const unsigned short* br1 = bp + (size_t)(64 + ar) * HID;

  const int lane = tid & 63;
  const int w = tid >> 6;
  const int wm = (w >> 1) * 64;
  const int wn = (w & 1) * 64;
  const int fr = lane & 15;
  const int fq = lane >> 4;

  f32x4 acc[4][4];
#pragma unroll
  for (int i = 0; i < 4; i++)
#pragma unroll
    for (int j = 0; j < 4; j++) acc[i][j] = (f32x4){0.f, 0.f, 0.f, 0.f};

  for (int k0 = 0; k0 < HID; k0 += 32) {
    f32x4 a0 = *(const f32x4*)(ha0 + k0);
    f32x4 a1 = *(const f32x4*)(ha1 + k0);
    f32x4 b0 = *(const f32x4*)(br0 + k0);
    f32x4 b1v = *(const f32x4*)(br1 + k0);
    __syncthreads();
    *(f32x4*)(As + ar * 40 + ac) = a0;
    *(f32x4*)(As + (64 + ar) * 40 + ac) = a1;
    *(f32x4*)(Bs + ar * 40 + ac) = b0;
    *(f32x4*)(Bs + (64 + ar) * 40 + ac) = b1v;
    __syncthreads();
    s16x8 af[4], bf[4];
#pragma unroll
    for (int i = 0; i < 4; i++) af[i] = *(const s16x8*)(As + (wm + i * 16 + fr) * 40 + fq * 8);
#pragma unroll
    for (int j = 0; j < 4; j++) bf[j] = *(const s16x8*)(Bs + (wn + j * 16 + fr) * 40 + fq * 8);
#pragma unroll
    for (int i = 0; i < 4; i++)
#pragma unroll
      for (int j = 0; j < 4; j++)
        acc[i][j] = __builtin_amdgcn_mfma_f32_16x16x32_bf16(af[i], bf[j], acc[i][j], 0, 0, 0);
  }

  const float* b2p = b2 + (size_t)e * DIM + nb * 128 + wn;
#pragma unroll
  for (int j = 0; j < 4; j++) {
    float bias = b2p[j * 16 + fr];
#pragma unroll
    for (int i = 0; i < 4; i++)
#pragma unroll
      for (int v = 0; v < 4; v++) {
        int m = wm + i * 16 + fq * 4 + v;
        int tok = toks[m];
        float g = gts[m];
        float val = g * (acc[i][j][v] + bias);
        atomicAdd(out + (size_t)tok * DIM + nb * 128 + wn + j * 16 + fr, val);
      }
  }
}

extern "C" void kernel_launch(void* const* d_in, const int* in_sizes, int n_in,
                              void* d_out, int out_size, void* d_ws, size_t ws_size,
                              hipStream_t stream) {
  const float* x     = (const float*)d_in[0];
  const float* noise = (const float*)d_in[1];
  const float* Wg    = (const float*)d_in[2];
  const float* bg    = (const float*)d_in[3];
  const float* Wn    = (const float*)d_in[4];
  const float* bn    = (const float*)d_in[5];
  const float* W1    = (const float*)d_in[6];
  const float* b1    = (const float*)d_in[7];
  const float* W2    = (const float*)d_in[8];
  const float* b2    = (const float*)d_in[9];
  float* out = (float*)d_out;

  char* ws = (char*)d_ws;
  int*            cnt   = (int*)(ws + 0);
  int*            hoff  = (int*)(ws + 32);
  int*            tokL  = (int*)(ws + 256);
  float*          gateL = (float*)(ws + 266496);
  unsigned short* xb    = (unsigned short*)(ws + 532736);
  unsigned short* w1t   = (unsigned short*)(ws + 17309952);
  unsigned short* w2t   = (unsigned short*)(ws + 84418816);
  unsigned short* hbuf  = (unsigned short*)(ws + 151527680);
  // total ws need: 294,134,016 bytes

  hipMemsetAsync(cnt, 0, 64, stream);
  hipMemsetAsync(out, 0, (size_t)TOK * DIM * sizeof(float), stream);

  cast_x_kernel<<<TOK * DIM / 4 / 256, 256, 0, stream>>>(x, xb);
  transpose_cast_kernel<<<dim3(HID / 64, DIM / 64, NE), 256, 0, stream>>>(W1, w1t, DIM, HID);
  transpose_cast_kernel<<<dim3(DIM / 64, HID / 64, NE), 256, 0, stream>>>(W2, w2t, HID, DIM);
  router_kernel<<<TOK / 4, 256, 0, stream>>>(x, noise, Wg, bg, Wn, bn, cnt, tokL, gateL);
  pad_kernel<<<1, 256, 0, stream>>>(cnt, hoff, tokL, gateL);
  gemm1_kernel<<<dim3(HID / 128, 64, NE), 256, 0, stream>>>(xb, w1t, b1, tokL, cnt, hoff, hbuf);
  gemm2_kernel<<<dim3(DIM / 128, 64, NE), 256, 0, stream>>>(hbuf, w2t, b2, tokL, gateL, cnt, hoff, out);
}

// Round 2
// 1069.374 us; speedup vs baseline: 1.0960x; 1.0960x over previous
//
#include <hip/hip_runtime.h>
#include <cstdint>

#define TOK   8192
#define DIM   1024
#define NE    8
#define HID   4096
#define CAP   8320
#define HROWS 17408

typedef __attribute__((ext_vector_type(4))) float f32x4;
typedef __attribute__((ext_vector_type(8))) short s16x8;

__device__ inline unsigned short f2bf(float f) {
  union { float f; unsigned u; } v; v.f = f;
  unsigned r = v.u + 0x7FFFu + ((v.u >> 16) & 1u);
  return (unsigned short)(r >> 16);
}

// async global->LDS, 16B per lane. LDS dest is wave-uniform base + lane*16.
__device__ __forceinline__ void gload_lds16(const void* gptr, void* lptr) {
  __builtin_amdgcn_global_load_lds(
      (const __attribute__((address_space(1))) unsigned*)gptr,
      (__attribute__((address_space(3))) unsigned*)lptr, 16, 0, 0);
}

// ---------------- cast x (fp32 -> bf16) ----------------
__global__ __launch_bounds__(256) void cast_x_kernel(const float* __restrict__ x,
                                                     unsigned short* __restrict__ xb) {
  size_t i = ((size_t)blockIdx.x * 256 + threadIdx.x) * 4;
  f32x4 v = *(const f32x4*)(x + i);
  ushort4 o;
  o.x = f2bf(v[0]); o.y = f2bf(v[1]); o.z = f2bf(v[2]); o.w = f2bf(v[3]);
  *(ushort4*)(xb + i) = o;
}

// ---------------- transpose+cast W [E][K][N] fp32 -> Wt [E][N][K] bf16 ----------------
__global__ __launch_bounds__(256) void transpose_cast_kernel(const float* __restrict__ W,
                                                             unsigned short* __restrict__ Wt,
                                                             int K, int N) {
  int e = blockIdx.z;
  int n0 = blockIdx.x * 64;
  int k0 = blockIdx.y * 64;
  const float* We = W + (size_t)e * K * N;
  unsigned short* Wte = Wt + (size_t)e * K * N;
  __shared__ float tile[64][65];
  int tid = threadIdx.x;
  int c4 = (tid & 15) * 4;  // 0..60
  int r  = tid >> 4;        // 0..15
#pragma unroll
  for (int rr = 0; rr < 64; rr += 16) {
    f32x4 v = *(const f32x4*)(We + (size_t)(k0 + r + rr) * N + n0 + c4);
    tile[r + rr][c4 + 0] = v[0];
    tile[r + rr][c4 + 1] = v[1];
    tile[r + rr][c4 + 2] = v[2];
    tile[r + rr][c4 + 3] = v[3];
  }
  __syncthreads();
#pragma unroll
  for (int rr = 0; rr < 64; rr += 16) {
    int n = r + rr;
    ushort4 o;
    o.x = f2bf(tile[c4 + 0][n]);
    o.y = f2bf(tile[c4 + 1][n]);
    o.z = f2bf(tile[c4 + 2][n]);
    o.w = f2bf(tile[c4 + 3][n]);
    *(ushort4*)(Wte + (size_t)(n0 + n) * K + k0 + c4) = o;
  }
}

// ---------------- router: one wave per token, fp32 exact ----------------
__global__ __launch_bounds__(256) void router_kernel(const float* __restrict__ x,
                                                     const float* __restrict__ noise,
                                                     const float* __restrict__ Wg,
                                                     const float* __restrict__ bg,
                                                     const float* __restrict__ Wn,
                                                     const float* __restrict__ bn,
                                                     int* __restrict__ cnt,
                                                     int* __restrict__ tokL,
                                                     float* __restrict__ gateL) {
  int t = blockIdx.x * 4 + (threadIdx.x >> 6);
  int lane = threadIdx.x & 63;
  float ag[8] = {0, 0, 0, 0, 0, 0, 0, 0};
  float an[8] = {0, 0, 0, 0, 0, 0, 0, 0};
  const float* xr = x + (size_t)t * DIM;
  for (int d = lane; d < DIM; d += 64) {
    float xv = xr[d];
    f32x4 g0 = *(const f32x4*)(Wg + d * 8);
    f32x4 g1 = *(const f32x4*)(Wg + d * 8 + 4);
    f32x4 n0 = *(const f32x4*)(Wn + d * 8);
    f32x4 n1 = *(const f32x4*)(Wn + d * 8 + 4);
    ag[0] += xv * g0[0]; ag[1] += xv * g0[1]; ag[2] += xv * g0[2]; ag[3] += xv * g0[3];
    ag[4] += xv * g1[0]; ag[5] += xv * g1[1]; ag[6] += xv * g1[2]; ag[7] += xv * g1[3];
    an[0] += xv * n0[0]; an[1] += xv * n0[1]; an[2] += xv * n0[2]; an[3] += xv * n0[3];
    an[4] += xv * n1[0]; an[5] += xv * n1[1]; an[6] += xv * n1[2]; an[7] += xv * n1[3];
  }
#pragma unroll
  for (int off = 32; off >= 1; off >>= 1) {
#pragma unroll
    for (int e = 0; e < 8; e++) {
      ag[e] += __shfl_xor(ag[e], off);
      an[e] += __shfl_xor(an[e], off);
    }
  }
  if (lane == 0) {
    float v[8];
#pragma unroll
    for (int e = 0; e < 8; e++) {
      float lg = ag[e] + bg[e];
      float ln = an[e] + bn[e];
      float sp = (ln > 20.f) ? ln : log1pf(expf(ln));  // stable softplus
      v[e] = lg + noise[(size_t)t * 8 + e] * sp;
    }
    int i1 = 0; float m1 = v[0];
#pragma unroll
    for (int e = 1; e < 8; e++) { if (v[e] > m1) { m1 = v[e]; i1 = e; } }
    int i2 = -1; float m2 = -1e30f;
#pragma unroll
    for (int e = 0; e < 8; e++) { if (e != i1 && v[e] > m2) { m2 = v[e]; i2 = e; } }
    float e2 = expf(m2 - m1);
    float denom = 1.f + e2;
    float g1 = 1.f / denom;
    float g2 = e2 / denom;
    int p1 = atomicAdd(&cnt[i1], 1);
    tokL[i1 * CAP + p1] = t; gateL[i1 * CAP + p1] = g1;
    int p2 = atomicAdd(&cnt[i2], 1);
    tokL[i2 * CAP + p2] = t; gateL[i2 * CAP + p2] = g2;
  }
}

// ---------------- pad lists to 128-multiples; prefix-sum h offsets ----------------
__global__ __launch_bounds__(256) void pad_kernel(const int* __restrict__ cnt,
                                                  int* __restrict__ hoff,
                                                  int* __restrict__ tokL,
                                                  float* __restrict__ gateL) {
  __shared__ int cp_s[8];
  if (threadIdx.x == 0) {
    int off = 0;
    for (int e = 0; e < 8; e++) {
      int c = cnt[e];
      int cp = (c + 127) & ~127;
      cp_s[e] = cp;
      hoff[e] = off;
      off += cp;
    }
  }
  __syncthreads();
  for (int e = 0; e < 8; e++) {
    int c = cnt[e], cp = cp_s[e];
    for (int i = c + threadIdx.x; i < cp; i += 256) {
      tokL[e * CAP + i] = 0;
      gateL[e * CAP + i] = 0.f;
    }
  }
}

// ---------------- GEMM1: h = relu(gather(x) @ W1[e] + b1[e]) ----------------
// m97-style: global_load_lds width-16 staging, unpadded BK=32 LDS tiles.
__global__ __launch_bounds__(256) void gemm1_kernel(const unsigned short* __restrict__ xb,
                                                    const unsigned short* __restrict__ w1t,
                                                    const float* __restrict__ b1,
                                                    const int* __restrict__ tokL,
                                                    const int* __restrict__ cnt,
                                                    const int* __restrict__ hoff,
                                                    unsigned short* __restrict__ h) {
  const int e = blockIdx.z;
  const int c = cnt[e];
  const int cp = (c + 127) & ~127;
  const int rb = blockIdx.y;
  if (rb * 128 >= cp) return;
  const int nb = blockIdx.x;
  const int row0 = hoff[e] + rb * 128;

  __shared__ unsigned short As[128 * 32];  // unpadded: required by global_load_lds
  __shared__ unsigned short Bs[128 * 32];
  __shared__ int toks[128];

  const int tid = threadIdx.x;
  if (tid < 128) toks[tid] = tokL[e * CAP + rb * 128 + tid];
  __syncthreads();

  const int ar = tid >> 2;         // staging row 0..63 (and +64)
  const int ac = (tid & 3) << 3;   // bf16 col 0,8,16,24
  const unsigned short* ga0 = xb + (size_t)toks[ar] * DIM + ac;
  const unsigned short* ga1 = xb + (size_t)toks[64 + ar] * DIM + ac;
  const unsigned short* bp = w1t + (size_t)e * HID * DIM + (size_t)(nb * 128) * DIM + ac;
  const unsigned short* gb0 = bp + (size_t)ar * DIM;
  const unsigned short* gb1 = bp + (size_t)(64 + ar) * DIM;

  const int lane = tid & 63;
  const int w = tid >> 6;
  // wave-uniform LDS staging bases (lane*16B appended by HW)
  unsigned short* lA0 = As + w * 512;
  unsigned short* lA1 = As + w * 512 + 2048;
  unsigned short* lB0 = Bs + w * 512;
  unsigned short* lB1 = Bs + w * 512 + 2048;

  const int wm = (w >> 1) * 64;
  const int wn = (w & 1) * 64;
  const int fr = lane & 15;
  const int fq = lane >> 4;

  f32x4 acc[4][4];
#pragma unroll
  for (int i = 0; i < 4; i++)
#pragma unroll
    for (int j = 0; j < 4; j++) acc[i][j] = (f32x4){0.f, 0.f, 0.f, 0.f};

  for (int k0 = 0; k0 < DIM; k0 += 32) {
    __syncthreads();
    gload_lds16(ga0 + k0, lA0);
    gload_lds16(ga1 + k0, lA1);
    gload_lds16(gb0 + k0, lB0);
    gload_lds16(gb1 + k0, lB1);
    __syncthreads();
    s16x8 af[4], bf[4];
#pragma unroll
    for (int i = 0; i < 4; i++) af[i] = *(const s16x8*)(As + (wm + i * 16 + fr) * 32 + fq * 8);
#pragma unroll
    for (int j = 0; j < 4; j++) bf[j] = *(const s16x8*)(Bs + (wn + j * 16 + fr) * 32 + fq * 8);
#pragma unroll
    for (int i = 0; i < 4; i++)
#pragma unroll
      for (int j = 0; j < 4; j++)
        acc[i][j] = __builtin_amdgcn_mfma_f32_16x16x32_bf16(af[i], bf[j], acc[i][j], 0, 0, 0);
  }

  const float* b1p = b1 + (size_t)e * HID + nb * 128 + wn;
#pragma unroll
  for (int j = 0; j < 4; j++) {
    float bias = b1p[j * 16 + fr];
#pragma unroll
    for (int i = 0; i < 4; i++)
#pragma unroll
      for (int v = 0; v < 4; v++) {
        float val = acc[i][j][v] + bias;
        val = fmaxf(val, 0.f);
        int m = wm + i * 16 + fq * 4 + v;
        h[(size_t)(row0 + m) * HID + nb * 128 + wn + j * 16 + fr] = f2bf(val);
      }
  }
}

// ---------------- GEMM2: out[tok] += gate * (h @ W2[e] + b2[e]) ----------------
__global__ __launch_bounds__(256) void gemm2_kernel(const unsigned short* __restrict__ h,
                                                    const unsigned short* __restrict__ w2t,
                                                    const float* __restrict__ b2,
                                                    const int* __restrict__ tokL,
                                                    const float* __restrict__ gateL,
                                                    const int* __restrict__ cnt,
                                                    const int* __restrict__ hoff,
                                                    float* __restrict__ out) {
  const int e = blockIdx.z;
  const int c = cnt[e];
  const int cp = (c + 127) & ~127;
  const int rb = blockIdx.y;
  if (rb * 128 >= cp) return;
  const int nb = blockIdx.x;
  const int row0 = hoff[e] + rb * 128;

  __shared__ unsigned short As[128 * 32];
  __shared__ unsigned short Bs[128 * 32];
  __shared__ int toks[128];
  __shared__ float gts[128];

  const int tid = threadIdx.x;
  if (tid < 128) {
    toks[tid] = tokL[e * CAP + rb * 128 + tid];
    gts[tid] = gateL[e * CAP + rb * 128 + tid];
  }
  __syncthreads();

  const int ar = tid >> 2;
  const int ac = (tid & 3) << 3;
  const unsigned short* ga0 = h + (size_t)(row0 + ar) * HID + ac;
  const unsigned short* ga1 = h + (size_t)(row0 + 64 + ar) * HID + ac;
  const unsigned short* bp = w2t + (size_t)e * DIM * HID + (size_t)(nb * 128) * HID + ac;
  const unsigned short* gb0 = bp + (size_t)ar * HID;
  const unsigned short* gb1 = bp + (size_t)(64 + ar) * HID;

  const int lane = tid & 63;
  const int w = tid >> 6;
  unsigned short* lA0 = As + w * 512;
  unsigned short* lA1 = As + w * 512 + 2048;
  unsigned short* lB0 = Bs + w * 512;
  unsigned short* lB1 = Bs + w * 512 + 2048;

  const int wm = (w >> 1) * 64;
  const int wn = (w & 1) * 64;
  const int fr = lane & 15;
  const int fq = lane >> 4;

  f32x4 acc[4][4];
#pragma unroll
  for (int i = 0; i < 4; i++)
#pragma unroll
    for (int j = 0; j < 4; j++) acc[i][j] = (f32x4){0.f, 0.f, 0.f, 0.f};

  for (int k0 = 0; k0 < HID; k0 += 32) {
    __syncthreads();
    gload_lds16(ga0 + k0, lA0);
    gload_lds16(ga1 + k0, lA1);
    gload_lds16(gb0 + k0, lB0);
    gload_lds16(gb1 + k0, lB1);
    __syncthreads();
    s16x8 af[4], bf[4];
#pragma unroll
    for (int i = 0; i < 4; i++) af[i] = *(const s16x8*)(As + (wm + i * 16 + fr) * 32 + fq * 8);
#pragma unroll
    for (int j = 0; j < 4; j++) bf[j] = *(const s16x8*)(Bs + (wn + j * 16 + fr) * 32 + fq * 8);
#pragma unroll
    for (int i = 0; i < 4; i++)
#pragma unroll
      for (int j = 0; j < 4; j++)
        acc[i][j] = __builtin_amdgcn_mfma_f32_16x16x32_bf16(af[i], bf[j], acc[i][j], 0, 0, 0);
  }

  const float* b2p = b2 + (size_t)e * DIM + nb * 128 + wn;
#pragma unroll
  for (int j = 0; j < 4; j++) {
    float bias = b2p[j * 16 + fr];
#pragma unroll
    for (int i = 0; i < 4; i++)
#pragma unroll
      for (int v = 0; v < 4; v++) {
        int m = wm + i * 16 + fq * 4 + v;
        int tok = toks[m];
        float g = gts[m];
        float val = g * (acc[i][j][v] + bias);
        atomicAdd(out + (size_t)tok * DIM + nb * 128 + wn + j * 16 + fr, val);
      }
  }
}

extern "C" void kernel_launch(void* const* d_in, const int* in_sizes, int n_in,
                              void* d_out, int out_size, void* d_ws, size_t ws_size,
                              hipStream_t stream) {
  const float* x     = (const float*)d_in[0];
  const float* noise = (const float*)d_in[1];
  const float* Wg    = (const float*)d_in[2];
  const float* bg    = (const float*)d_in[3];
  const float* Wn    = (const float*)d_in[4];
  const float* bn    = (const float*)d_in[5];
  const float* W1    = (const float*)d_in[6];
  const float* b1    = (const float*)d_in[7];
  const float* W2    = (const float*)d_in[8];
  const float* b2    = (const float*)d_in[9];
  float* out = (float*)d_out;

  char* ws = (char*)d_ws;
  int*            cnt   = (int*)(ws + 0);
  int*            hoff  = (int*)(ws + 32);
  int*            tokL  = (int*)(ws + 256);
  float*          gateL = (float*)(ws + 266496);
  unsigned short* xb    = (unsigned short*)(ws + 532736);
  unsigned short* w1t   = (unsigned short*)(ws + 17309952);
  unsigned short* w2t   = (unsigned short*)(ws + 84418816);
  unsigned short* hbuf  = (unsigned short*)(ws + 151527680);
  // total ws need: 294,134,016 bytes

  hipMemsetAsync(cnt, 0, 64, stream);
  hipMemsetAsync(out, 0, (size_t)TOK * DIM * sizeof(float), stream);

  cast_x_kernel<<<TOK * DIM / 4 / 256, 256, 0, stream>>>(x, xb);
  transpose_cast_kernel<<<dim3(HID / 64, DIM / 64, NE), 256, 0, stream>>>(W1, w1t, DIM, HID);
  transpose_cast_kernel<<<dim3(DIM / 64, HID / 64, NE), 256, 0, stream>>>(W2, w2t, HID, DIM);
  router_kernel<<<TOK / 4, 256, 0, stream>>>(x, noise, Wg, bg, Wn, bn, cnt, tokL, gateL);
  pad_kernel<<<1, 256, 0, stream>>>(cnt, hoff, tokL, gateL);
  gemm1_kernel<<<dim3(HID / 128, 64, NE), 256, 0, stream>>>(xb, w1t, b1, tokL, cnt, hoff, hbuf);
  gemm2_kernel<<<dim3(DIM / 128, 64, NE), 256, 0, stream>>>(hbuf, w2t, b2, tokL, gateL, cnt, hoff, out);
}

// Round 3
// 969.843 us; speedup vs baseline: 1.2085x; 1.1026x over previous
//
#include <hip/hip_runtime.h>
#include <cstdint>

#define TOK   8192
#define DIM   1024
#define NE    8
#define HID   4096
#define CAP   8320
#define HROWS 17408

typedef __attribute__((ext_vector_type(4))) float f32x4;
typedef __attribute__((ext_vector_type(8))) short s16x8;

__device__ inline unsigned short f2bf(float f) {
  union { float f; unsigned u; } v; v.f = f;
  unsigned r = v.u + 0x7FFFu + ((v.u >> 16) & 1u);
  return (unsigned short)(r >> 16);
}
__device__ inline float bf2f(unsigned short u) {
  union { unsigned u; float f; } v; v.u = ((unsigned)u) << 16;
  return v.f;
}

// async global->LDS, 16B per lane. LDS dest is wave-uniform base + lane*16.
__device__ __forceinline__ void gload_lds16(const void* gptr, void* lptr) {
  __builtin_amdgcn_global_load_lds(
      (const __attribute__((address_space(1))) unsigned*)gptr,
      (__attribute__((address_space(3))) unsigned*)lptr, 16, 0, 0);
}

// ---------------- cast x (fp32 -> bf16) ----------------
__global__ __launch_bounds__(256) void cast_x_kernel(const float* __restrict__ x,
                                                     unsigned short* __restrict__ xb) {
  size_t i = ((size_t)blockIdx.x * 256 + threadIdx.x) * 4;
  f32x4 v = *(const f32x4*)(x + i);
  ushort4 o;
  o.x = f2bf(v[0]); o.y = f2bf(v[1]); o.z = f2bf(v[2]); o.w = f2bf(v[3]);
  *(ushort4*)(xb + i) = o;
}

// ---------------- transpose+cast W [E][K][N] fp32 -> Wt [E][N][K] bf16 ----------------
__global__ __launch_bounds__(256) void transpose_cast_kernel(const float* __restrict__ W,
                                                             unsigned short* __restrict__ Wt,
                                                             int K, int N) {
  int e = blockIdx.z;
  int n0 = blockIdx.x * 64;
  int k0 = blockIdx.y * 64;
  const float* We = W + (size_t)e * K * N;
  unsigned short* Wte = Wt + (size_t)e * K * N;
  __shared__ float tile[64][65];
  int tid = threadIdx.x;
  int c4 = (tid & 15) * 4;  // 0..60
  int r  = tid >> 4;        // 0..15
#pragma unroll
  for (int rr = 0; rr < 64; rr += 16) {
    f32x4 v = *(const f32x4*)(We + (size_t)(k0 + r + rr) * N + n0 + c4);
    tile[r + rr][c4 + 0] = v[0];
    tile[r + rr][c4 + 1] = v[1];
    tile[r + rr][c4 + 2] = v[2];
    tile[r + rr][c4 + 3] = v[3];
  }
  __syncthreads();
#pragma unroll
  for (int rr = 0; rr < 64; rr += 16) {
    int n = r + rr;
    ushort4 o;
    o.x = f2bf(tile[c4 + 0][n]);
    o.y = f2bf(tile[c4 + 1][n]);
    o.z = f2bf(tile[c4 + 2][n]);
    o.w = f2bf(tile[c4 + 3][n]);
    *(ushort4*)(Wte + (size_t)(n0 + n) * K + k0 + c4) = o;
  }
}

// ---------------- router: one wave per token, fp32 exact ----------------
// Also records each token's two (expert,pos) slots for the atomic-free combine.
__global__ __launch_bounds__(256) void router_kernel(const float* __restrict__ x,
                                                     const float* __restrict__ noise,
                                                     const float* __restrict__ Wg,
                                                     const float* __restrict__ bg,
                                                     const float* __restrict__ Wn,
                                                     const float* __restrict__ bn,
                                                     int* __restrict__ cnt,
                                                     int* __restrict__ tokL,
                                                     float* __restrict__ gateL,
                                                     int* __restrict__ tokmap) {
  int t = blockIdx.x * 4 + (threadIdx.x >> 6);
  int lane = threadIdx.x & 63;
  float ag[8] = {0, 0, 0, 0, 0, 0, 0, 0};
  float an[8] = {0, 0, 0, 0, 0, 0, 0, 0};
  const float* xr = x + (size_t)t * DIM;
  for (int d = lane; d < DIM; d += 64) {
    float xv = xr[d];
    f32x4 g0 = *(const f32x4*)(Wg + d * 8);
    f32x4 g1 = *(const f32x4*)(Wg + d * 8 + 4);
    f32x4 n0 = *(const f32x4*)(Wn + d * 8);
    f32x4 n1 = *(const f32x4*)(Wn + d * 8 + 4);
    ag[0] += xv * g0[0]; ag[1] += xv * g0[1]; ag[2] += xv * g0[2]; ag[3] += xv * g0[3];
    ag[4] += xv * g1[0]; ag[5] += xv * g1[1]; ag[6] += xv * g1[2]; ag[7] += xv * g1[3];
    an[0] += xv * n0[0]; an[1] += xv * n0[1]; an[2] += xv * n0[2]; an[3] += xv * n0[3];
    an[4] += xv * n1[0]; an[5] += xv * n1[1]; an[6] += xv * n1[2]; an[7] += xv * n1[3];
  }
#pragma unroll
  for (int off = 32; off >= 1; off >>= 1) {
#pragma unroll
    for (int e = 0; e < 8; e++) {
      ag[e] += __shfl_xor(ag[e], off);
      an[e] += __shfl_xor(an[e], off);
    }
  }
  if (lane == 0) {
    float v[8];
#pragma unroll
    for (int e = 0; e < 8; e++) {
      float lg = ag[e] + bg[e];
      float ln = an[e] + bn[e];
      float sp = (ln > 20.f) ? ln : log1pf(expf(ln));  // stable softplus
      v[e] = lg + noise[(size_t)t * 8 + e] * sp;
    }
    int i1 = 0; float m1 = v[0];
#pragma unroll
    for (int e = 1; e < 8; e++) { if (v[e] > m1) { m1 = v[e]; i1 = e; } }
    int i2 = -1; float m2 = -1e30f;
#pragma unroll
    for (int e = 0; e < 8; e++) { if (e != i1 && v[e] > m2) { m2 = v[e]; i2 = e; } }
    float e2 = expf(m2 - m1);
    float denom = 1.f + e2;
    float g1 = 1.f / denom;
    float g2 = e2 / denom;
    int p1 = atomicAdd(&cnt[i1], 1);
    tokL[i1 * CAP + p1] = t; gateL[i1 * CAP + p1] = g1;
    int p2 = atomicAdd(&cnt[i2], 1);
    tokL[i2 * CAP + p2] = t; gateL[i2 * CAP + p2] = g2;
    tokmap[t * 2 + 0] = (i1 << 20) | p1;
    tokmap[t * 2 + 1] = (i2 << 20) | p2;
  }
}

// ---------------- pad lists to 128-multiples; prefix-sum h offsets ----------------
__global__ __launch_bounds__(256) void pad_kernel(const int* __restrict__ cnt,
                                                  int* __restrict__ hoff,
                                                  int* __restrict__ tokL,
                                                  float* __restrict__ gateL) {
  __shared__ int cp_s[8];
  if (threadIdx.x == 0) {
    int off = 0;
    for (int e = 0; e < 8; e++) {
      int c = cnt[e];
      int cp = (c + 127) & ~127;
      cp_s[e] = cp;
      hoff[e] = off;
      off += cp;
    }
  }
  __syncthreads();
  for (int e = 0; e < 8; e++) {
    int c = cnt[e], cp = cp_s[e];
    for (int i = c + threadIdx.x; i < cp; i += 256) {
      tokL[e * CAP + i] = 0;
      gateL[e * CAP + i] = 0.f;
    }
  }
}

// ---------------- GEMM1: h = relu(gather(x) @ W1[e] + b1[e]) ----------------
__global__ __launch_bounds__(256) void gemm1_kernel(const unsigned short* __restrict__ xb,
                                                    const unsigned short* __restrict__ w1t,
                                                    const float* __restrict__ b1,
                                                    const int* __restrict__ tokL,
                                                    const int* __restrict__ cnt,
                                                    const int* __restrict__ hoff,
                                                    unsigned short* __restrict__ h) {
  const int e = blockIdx.z;
  const int c = cnt[e];
  const int cp = (c + 127) & ~127;
  const int rb = blockIdx.y;
  if (rb * 128 >= cp) return;
  const int nb = blockIdx.x;
  const int row0 = hoff[e] + rb * 128;

  __shared__ unsigned short As[128 * 32];  // unpadded: required by global_load_lds
  __shared__ unsigned short Bs[128 * 32];
  __shared__ int toks[128];

  const int tid = threadIdx.x;
  if (tid < 128) toks[tid] = tokL[e * CAP + rb * 128 + tid];
  __syncthreads();

  const int ar = tid >> 2;         // staging row 0..63 (and +64)
  const int ac = (tid & 3) << 3;   // bf16 col 0,8,16,24
  const unsigned short* ga0 = xb + (size_t)toks[ar] * DIM + ac;
  const unsigned short* ga1 = xb + (size_t)toks[64 + ar] * DIM + ac;
  const unsigned short* bp = w1t + (size_t)e * HID * DIM + (size_t)(nb * 128) * DIM + ac;
  const unsigned short* gb0 = bp + (size_t)ar * DIM;
  const unsigned short* gb1 = bp + (size_t)(64 + ar) * DIM;

  const int lane = tid & 63;
  const int w = tid >> 6;
  unsigned short* lA0 = As + w * 512;
  unsigned short* lA1 = As + w * 512 + 2048;
  unsigned short* lB0 = Bs + w * 512;
  unsigned short* lB1 = Bs + w * 512 + 2048;

  const int wm = (w >> 1) * 64;
  const int wn = (w & 1) * 64;
  const int fr = lane & 15;
  const int fq = lane >> 4;

  f32x4 acc[4][4];
#pragma unroll
  for (int i = 0; i < 4; i++)
#pragma unroll
    for (int j = 0; j < 4; j++) acc[i][j] = (f32x4){0.f, 0.f, 0.f, 0.f};

  for (int k0 = 0; k0 < DIM; k0 += 32) {
    __syncthreads();
    gload_lds16(ga0 + k0, lA0);
    gload_lds16(ga1 + k0, lA1);
    gload_lds16(gb0 + k0, lB0);
    gload_lds16(gb1 + k0, lB1);
    __syncthreads();
    s16x8 af[4], bf[4];
#pragma unroll
    for (int i = 0; i < 4; i++) af[i] = *(const s16x8*)(As + (wm + i * 16 + fr) * 32 + fq * 8);
#pragma unroll
    for (int j = 0; j < 4; j++) bf[j] = *(const s16x8*)(Bs + (wn + j * 16 + fr) * 32 + fq * 8);
#pragma unroll
    for (int i = 0; i < 4; i++)
#pragma unroll
      for (int j = 0; j < 4; j++)
        acc[i][j] = __builtin_amdgcn_mfma_f32_16x16x32_bf16(af[i], bf[j], acc[i][j], 0, 0, 0);
  }

  const float* b1p = b1 + (size_t)e * HID + nb * 128 + wn;
#pragma unroll
  for (int j = 0; j < 4; j++) {
    float bias = b1p[j * 16 + fr];
#pragma unroll
    for (int i = 0; i < 4; i++)
#pragma unroll
      for (int v = 0; v < 4; v++) {
        float val = acc[i][j][v] + bias;
        val = fmaxf(val, 0.f);
        int m = wm + i * 16 + fq * 4 + v;
        h[(size_t)(row0 + m) * HID + nb * 128 + wn + j * 16 + fr] = f2bf(val);
      }
  }
}

// ---------------- GEMM2: ybuf[row] = h[row] @ W2[e] + b2[e]  (bf16, no gate, no atomics)
__global__ __launch_bounds__(256) void gemm2_kernel(const unsigned short* __restrict__ h,
                                                    const unsigned short* __restrict__ w2t,
                                                    const float* __restrict__ b2,
                                                    const int* __restrict__ cnt,
                                                    const int* __restrict__ hoff,
                                                    unsigned short* __restrict__ ybuf) {
  const int e = blockIdx.z;
  const int c = cnt[e];
  const int cp = (c + 127) & ~127;
  const int rb = blockIdx.y;
  if (rb * 128 >= cp) return;
  const int nb = blockIdx.x;
  const int row0 = hoff[e] + rb * 128;

  __shared__ unsigned short As[128 * 32];
  __shared__ unsigned short Bs[128 * 32];

  const int tid = threadIdx.x;
  const int ar = tid >> 2;
  const int ac = (tid & 3) << 3;
  const unsigned short* ga0 = h + (size_t)(row0 + ar) * HID + ac;
  const unsigned short* ga1 = h + (size_t)(row0 + 64 + ar) * HID + ac;
  const unsigned short* bp = w2t + (size_t)e * DIM * HID + (size_t)(nb * 128) * HID + ac;
  const unsigned short* gb0 = bp + (size_t)ar * HID;
  const unsigned short* gb1 = bp + (size_t)(64 + ar) * HID;

  const int lane = tid & 63;
  const int w = tid >> 6;
  unsigned short* lA0 = As + w * 512;
  unsigned short* lA1 = As + w * 512 + 2048;
  unsigned short* lB0 = Bs + w * 512;
  unsigned short* lB1 = Bs + w * 512 + 2048;

  const int wm = (w >> 1) * 64;
  const int wn = (w & 1) * 64;
  const int fr = lane & 15;
  const int fq = lane >> 4;

  f32x4 acc[4][4];
#pragma unroll
  for (int i = 0; i < 4; i++)
#pragma unroll
    for (int j = 0; j < 4; j++) acc[i][j] = (f32x4){0.f, 0.f, 0.f, 0.f};

  for (int k0 = 0; k0 < HID; k0 += 32) {
    __syncthreads();
    gload_lds16(ga0 + k0, lA0);
    gload_lds16(ga1 + k0, lA1);
    gload_lds16(gb0 + k0, lB0);
    gload_lds16(gb1 + k0, lB1);
    __syncthreads();
    s16x8 af[4], bf[4];
#pragma unroll
    for (int i = 0; i < 4; i++) af[i] = *(const s16x8*)(As + (wm + i * 16 + fr) * 32 + fq * 8);
#pragma unroll
    for (int j = 0; j < 4; j++) bf[j] = *(const s16x8*)(Bs + (wn + j * 16 + fr) * 32 + fq * 8);
#pragma unroll
    for (int i = 0; i < 4; i++)
#pragma unroll
      for (int j = 0; j < 4; j++)
        acc[i][j] = __builtin_amdgcn_mfma_f32_16x16x32_bf16(af[i], bf[j], acc[i][j], 0, 0, 0);
  }

  const float* b2p = b2 + (size_t)e * DIM + nb * 128 + wn;
#pragma unroll
  for (int j = 0; j < 4; j++) {
    float bias = b2p[j * 16 + fr];
#pragma unroll
    for (int i = 0; i < 4; i++)
#pragma unroll
      for (int v = 0; v < 4; v++) {
        int m = wm + i * 16 + fq * 4 + v;
        ybuf[(size_t)(row0 + m) * DIM + nb * 128 + wn + j * 16 + fr] =
            f2bf(acc[i][j][v] + bias);
      }
  }
}

// ---------------- combine: out[t] = g1*ybuf[row1] + g2*ybuf[row2] (dense, coalesced)
__global__ __launch_bounds__(256) void combine_kernel(const unsigned short* __restrict__ ybuf,
                                                      const int* __restrict__ tokmap,
                                                      const float* __restrict__ gateL,
                                                      const int* __restrict__ hoff,
                                                      float* __restrict__ out) {
  const int t = blockIdx.x;
  const int m1 = tokmap[t * 2 + 0];
  const int m2 = tokmap[t * 2 + 1];
  const int e1 = m1 >> 20, p1 = m1 & 0xFFFFF;
  const int e2 = m2 >> 20, p2 = m2 & 0xFFFFF;
  const float g1 = gateL[e1 * CAP + p1];
  const float g2 = gateL[e2 * CAP + p2];
  const size_t r1 = (size_t)(hoff[e1] + p1) * DIM;
  const size_t r2 = (size_t)(hoff[e2] + p2) * DIM;
  const int d = threadIdx.x * 4;
  ushort4 u1 = *(const ushort4*)(ybuf + r1 + d);
  ushort4 u2 = *(const ushort4*)(ybuf + r2 + d);
  f32x4 o;
  o[0] = g1 * bf2f(u1.x) + g2 * bf2f(u2.x);
  o[1] = g1 * bf2f(u1.y) + g2 * bf2f(u2.y);
  o[2] = g1 * bf2f(u1.z) + g2 * bf2f(u2.z);
  o[3] = g1 * bf2f(u1.w) + g2 * bf2f(u2.w);
  *(f32x4*)(out + (size_t)t * DIM + d) = o;
}

extern "C" void kernel_launch(void* const* d_in, const int* in_sizes, int n_in,
                              void* d_out, int out_size, void* d_ws, size_t ws_size,
                              hipStream_t stream) {
  const float* x     = (const float*)d_in[0];
  const float* noise = (const float*)d_in[1];
  const float* Wg    = (const float*)d_in[2];
  const float* bg    = (const float*)d_in[3];
  const float* Wn    = (const float*)d_in[4];
  const float* bn    = (const float*)d_in[5];
  const float* W1    = (const float*)d_in[6];
  const float* b1    = (const float*)d_in[7];
  const float* W2    = (const float*)d_in[8];
  const float* b2    = (const float*)d_in[9];
  float* out = (float*)d_out;

  char* ws = (char*)d_ws;
  int*            cnt    = (int*)(ws + 0);
  int*            hoff   = (int*)(ws + 32);
  int*            tokL   = (int*)(ws + 256);
  float*          gateL  = (float*)(ws + 266496);
  unsigned short* xb     = (unsigned short*)(ws + 532736);
  unsigned short* w1t    = (unsigned short*)(ws + 17309952);   // dead after gemm1
  unsigned short* w2t    = (unsigned short*)(ws + 84418816);
  unsigned short* hbuf   = (unsigned short*)(ws + 151527680);
  int*            tokmap = (int*)(ws + 294134016);
  // ybuf reuses the w1t region (w1t is 67 MB, ybuf needs 35.7 MB; gemm1 finishes
  // reading w1t before gemm2 writes ybuf — same-stream ordering guarantees it).
  unsigned short* ybuf   = w1t;
  // total ws need: 294,199,552 bytes

  hipMemsetAsync(cnt, 0, 64, stream);

  cast_x_kernel<<<TOK * DIM / 4 / 256, 256, 0, stream>>>(x, xb);
  transpose_cast_kernel<<<dim3(HID / 64, DIM / 64, NE), 256, 0, stream>>>(W1, w1t, DIM, HID);
  transpose_cast_kernel<<<dim3(DIM / 64, HID / 64, NE), 256, 0, stream>>>(W2, w2t, HID, DIM);
  router_kernel<<<TOK / 4, 256, 0, stream>>>(x, noise, Wg, bg, Wn, bn, cnt, tokL, gateL, tokmap);
  pad_kernel<<<1, 256, 0, stream>>>(cnt, hoff, tokL, gateL);
  gemm1_kernel<<<dim3(HID / 128, 64, NE), 256, 0, stream>>>(xb, w1t, b1, tokL, cnt, hoff, hbuf);
  gemm2_kernel<<<dim3(DIM / 128, 64, NE), 256, 0, stream>>>(hbuf, w2t, b2, cnt, hoff, ybuf);
  combine_kernel<<<TOK, 256, 0, stream>>>(ybuf, tokmap, gateL, hoff, out);
}